// Round 3
// baseline (106.104 us; speedup 1.0000x reference)
//
#include <hip/hip_runtime.h>
#include <hip/hip_bf16.h>

#define SEQ 2048
#define EMB 1024
#define DH  128
#define QSCALE 0.08838834764831845f  // 1/sqrt(128)

typedef __attribute__((ext_vector_type(4))) float f32x4;
typedef __attribute__((ext_vector_type(8))) short bf16x8;
typedef __attribute__((ext_vector_type(4))) short bf16x4;

__device__ __forceinline__ short f2bf(float f) {
  unsigned u = __builtin_bit_cast(unsigned, f);
  u += 0x7fffu + ((u >> 16) & 1u);   // RNE
  return (short)(u >> 16);
}

__device__ __forceinline__ float bf2f(short s) {
  unsigned u = ((unsigned)(unsigned short)s) << 16;
  return __builtin_bit_cast(float, u);
}

__device__ __forceinline__ f32x4 mfma16(bf16x8 a, bf16x8 b, f32x4 c) {
  return __builtin_amdgcn_mfma_f32_16x16x32_bf16(a, b, c, 0, 0, 0);
}

// async global->LDS, 16B per lane; lds_base must be wave-uniform (HW adds lane*16)
__device__ __forceinline__ void gl_lds16(void* lds_base, const void* gsrc) {
  __builtin_amdgcn_global_load_lds(
      (const __attribute__((address_space(1))) void*)gsrc,
      (__attribute__((address_space(3))) void*)lds_base, 16, 0, 0);
}

// ---------------- weight prep ----------------
// W[E][128] f32 -> wt[p][kk][nb][lane][8] bf16 (exact B-fragment order for
// mfma_f32_16x16x32_bf16: lane l holds B[k = kk*32 + (l>>4)*8 + j][n = nb*16 + (l&15)]).
__global__ void prep_weights(const float* __restrict__ Wq, const float* __restrict__ Wk,
                             const float* __restrict__ Wv, short* __restrict__ wt) {
  int gid = blockIdx.x * 256 + threadIdx.x;
  int lane = gid & 63, c = lane & 15, g = (lane >> 4) & 3;
  int nb = (gid >> 6) & 7;
  int kk = (gid >> 9) & 31;
  int p = gid >> 14;
  const float* W = (p == 0) ? Wq : ((p == 1) ? Wk : Wv);
  bf16x8 v;
#pragma unroll
  for (int j = 0; j < 8; ++j)
    v[j] = f2bf(W[(kk * 32 + g * 8 + j) * DH + nb * 16 + c]);
  *(bf16x8*)(&wt[(size_t)gid * 8]) = v;
}

// ---------------- projection GEMM ----------------
// Theory: all prior versions read X in 128B granules (K_STEP*4B per row) -> ~1.2 TB/s
// HBM wall. This version stages A in KC=128 chunks: each global_load_lds reads
// CONTIGUOUS 512B row-segments (4x granule). Compute still consumes K=32 sub-steps.
// 1 wave/block, 32 rows/wave; A: 2-slot LDS ring (2x16KB -> 5 blocks/CU); W: per-lane
// 16B loads from fragment-ordered wt (L2-resident) into a 3-deep register ring.
// Fully unrolled 32 sub-steps with exact counted vmcnt; zero barriers.
__global__ __launch_bounds__(64, 2) void proj_gemm(
    const float* __restrict__ Xq, const float* __restrict__ Xk, const float* __restrict__ Xv,
    const short* __restrict__ wt,
    const float* __restrict__ bq, const float* __restrict__ bk, const float* __restrict__ bv,
    short* __restrict__ qp, short* __restrict__ kp, short* __restrict__ vt) {
  __shared__ f32x4 a_lds4[2][1024];   // 2 x 16KB: [slot][32 rows x 512B]
  char* a_lds = (char*)a_lds4;

  const int lane = threadIdx.x;
  const int g = lane >> 4, c = lane & 15;
  const int wid = blockIdx.x;
  const int p = wid >> 9, mb = wid & 511;
  const int row0 = mb << 5;                         // 32-row tile
  const float* X    = (p == 0) ? Xq : ((p == 1) ? Xk : Xv);
  const float* bias = (p == 0) ? bq : ((p == 1) ? bk : bv);
  const char* Xb  = (const char*)X;
  const char* WT  = (const char*)wt + (size_t)p * 262144;

  f32x4 acc[2][8];
#pragma unroll
  for (int rb = 0; rb < 2; ++rb)
#pragma unroll
    for (int nb = 0; nb < 8; ++nb) acc[rb][nb] = (f32x4){0.f, 0.f, 0.f, 0.f};

  bf16x8 wr[3][8];   // W register ring; all indices compile-time after unroll

  // Stage one KC=128 A-chunk (32 rows x 512B) into LDS slot. Each of 16 gl_lds reads
  // two contiguous 512B row segments. Source pre-XOR-swizzled within each row's 512B
  // (involution, 16B granularity) so the read side is bank-conflict-free.
  auto stage_A = [&](int slot, int kc) {
#pragma unroll
    for (int j = 0; j < 16; ++j) {
      int phys = j * 1024 + lane * 16;
      int row = phys >> 9;
      int off = phys & 511;
      gl_lds16(a_lds + slot * 16384 + j * 1024,
               Xb + (size_t)(row0 + row) * 4096 + kc * 512 + (off ^ ((row & 7) << 4)));
    }
  };

  auto loadW = [&](bf16x8* dst, int t) {
#pragma unroll
    for (int nb = 0; nb < 8; ++nb)
      dst[nb] = *(const bf16x8*)(WT + (size_t)t * 8192 + nb * 1024 + lane * 16);
  };

  auto compute = [&](const bf16x8* wf, int t) {
    int slot = (t >> 2) & 1, s = t & 3;
    const char* ab = a_lds + slot * 16384;
#pragma unroll
    for (int rb = 0; rb < 2; ++rb) {
      int r = (rb << 4) + c;
      int ad = (r << 9) + (((s << 7) + (g << 5)) ^ ((r & 7) << 4));
      f32x4 lo = *(const f32x4*)(ab + ad);
      f32x4 hi = *(const f32x4*)(ab + (ad ^ 16));
      bf16x8 a;
#pragma unroll
      for (int j = 0; j < 4; ++j) { a[j] = f2bf(lo[j]); a[4 + j] = f2bf(hi[j]); }
#pragma unroll
      for (int nb = 0; nb < 8; ++nb) acc[rb][nb] = mfma16(a, wf[nb], acc[rb][nb]);
    }
  };

  // Prologue: A(0) + W(0),W(1) in flight.
  stage_A(0, 0);
  loadW(wr[0], 0);
  loadW(wr[1], 1);
  __builtin_amdgcn_sched_barrier(0);

  // FIFO accounting (issue order per region t: [A?][W(t+2)][wait][compute(t)]):
  //   need W(t) retired; newer-than-W(t) = W(t+1)+W(t+2) (+A16 if A issued at t or t-1)
  //   -> vmcnt = 16 normally, 32 at (t&3)>=2 && t<28 (A issued at t&3==2, kc<7),
  //      8 at t=30, 0 at t=31. A(kc) is always older than the wait that first needs it.
#pragma unroll
  for (int t = 0; t < 32; ++t) {
    if ((t & 3) == 2 && t < 28)
      stage_A(((t >> 2) + 1) & 1, (t >> 2) + 1);
    if (t + 2 < 32)
      loadW(wr[(t + 2) % 3], t + 2);
    __builtin_amdgcn_sched_barrier(0);
    if (t == 31)                         asm volatile("s_waitcnt vmcnt(0)" ::: "memory");
    else if (t == 30)                    asm volatile("s_waitcnt vmcnt(8)" ::: "memory");
    else if ((t & 3) >= 2 && t < 28)     asm volatile("s_waitcnt vmcnt(32)" ::: "memory");
    else                                 asm volatile("s_waitcnt vmcnt(16)" ::: "memory");
    __builtin_amdgcn_sched_barrier(0);
    compute(wr[t % 3], t);
    __builtin_amdgcn_sched_barrier(0);
  }

  // epilogue: C/D layout col = c, row = g*4 + reg (within each 16-row sub-tile)
  float bvals[8];
#pragma unroll
  for (int nb = 0; nb < 8; ++nb) bvals[nb] = bias[nb * 16 + c];

  if (p < 2) {   // q (scaled) / k, row-major [token][128] bf16
    short* outp = (p == 0) ? qp : kp;
    float sc = (p == 0) ? QSCALE : 1.0f;
#pragma unroll
    for (int rb = 0; rb < 2; ++rb)
#pragma unroll
      for (int r = 0; r < 4; ++r) {
        int token = row0 + (rb << 4) + g * 4 + r;
#pragma unroll
        for (int nb = 0; nb < 8; ++nb)
          outp[token * 128 + nb * 16 + c] = f2bf((acc[rb][nb][r] + bvals[nb]) * sc);
      }
  } else {       // v transposed: vT[b][d][s] bf16
#pragma unroll
    for (int rb = 0; rb < 2; ++rb) {
      int tok0 = row0 + (rb << 4) + g * 4;
      int b_ = tok0 >> 11, s_ = tok0 & 2047;
#pragma unroll
      for (int nb = 0; nb < 8; ++nb) {
        int col = nb * 16 + c;
        bf16x4 v4;
#pragma unroll
        for (int r = 0; r < 4; ++r) v4[r] = f2bf(acc[rb][nb][r] + bvals[nb]);
        *(bf16x4*)(&vt[((size_t)(b_ * 128 + col)) * 2048 + s_]) = v4;
      }
    }
  }
}

// ---------------- avgV from projected V (degenerate-row fixup) ----------------
// avgv[b][d] = mean over padded s of vt[b][d][s]  (vt already includes bias)
__global__ __launch_bounds__(256) void avgv2_kernel(
    const short* __restrict__ vt, const int* __restrict__ pad,
    const float* __restrict__ bvv, float* __restrict__ avgv) {
  int b = blockIdx.x >> 3, dg = blockIdx.x & 7;
  int t = threadIdx.x, doff = t >> 4, sl = t & 15;
  int d = dg * 16 + doff;
  const short* vrow = vt + ((size_t)(b * 128 + d)) * 2048 + sl * 128;
  const int* prow = pad + (b << 11) + sl * 128;
  float sum = 0.f;
  int cnt = 0;
  for (int i = 0; i < 16; ++i) {
    bf16x8 v8 = *(const bf16x8*)(vrow + i * 8);
#pragma unroll
    for (int j = 0; j < 8; ++j) {
      int pd = prow[i * 8 + j];
      cnt += (pd != 0);
      if (pd) sum += bf2f(v8[j]);
    }
  }
#pragma unroll
  for (int xm = 1; xm < 16; xm <<= 1) {
    sum += __shfl_xor(sum, xm, 64);
    cnt += __shfl_xor(cnt, xm, 64);
  }
  if (sl == 0) avgv[(b << 7) + d] = (cnt > 0) ? (sum / (float)cnt) : 0.f;
  (void)bvv;
}

// ---------------- flash attention (causal, split-KV x2, double-buffered) ----------------
__device__ __forceinline__ void stage_kv(short* kb, short* vb,
                                         const char* kb_base, const char* vb_base,
                                         int kt, int w, int lane) {
#pragma unroll
  for (int ch = w; ch < 16; ch += 4) {   // K tile [key][d], swizzled 256B rows
    int phys = ch * 1024 + lane * 16;
    int lg = phys ^ (((phys >> 8) & 7) << 4);
    gl_lds16((char*)kb + ch * 1024,
             kb_base + (size_t)(kt * 64 + (lg >> 8)) * 256 + (lg & 255));
  }
#pragma unroll
  for (int ch = w; ch < 16; ch += 4) {   // V^T tile [d][key], swizzled 128B rows
    int phys = ch * 1024 + lane * 16;
    int lg = phys ^ (((phys >> 7) & 7) << 4);
    gl_lds16((char*)vb + ch * 1024,
             vb_base + (size_t)(lg >> 7) * 4096 + kt * 128 + (lg & 127));
  }
}

template <bool CAUSAL>
__device__ __forceinline__ void attn_tile(
    const short* __restrict__ k_lds, const short* __restrict__ v_lds, short* __restrict__ p_w,
    const bf16x8 (&qf)[4], f32x4 (&acc_o)[8], float (&m_r)[4], float (&l_r)[4],
    const int* __restrict__ padp, int kt, int qrow_g, int g, int c) {
  f32x4 sc[4];
#pragma unroll
  for (int nb = 0; nb < 4; ++nb) sc[nb] = (f32x4){0.f, 0.f, 0.f, 0.f};
#pragma unroll
  for (int ks = 0; ks < 4; ++ks) {
    bf16x8 kf[4];
#pragma unroll
    for (int nb = 0; nb < 4; ++nb) {
      int n = (nb << 4) + c;
      int off = (n << 8) + (ks << 6) + (g << 4);
      kf[nb] = *(const bf16x8*)((const char*)k_lds + (off ^ ((n & 7) << 4)));
    }
#pragma unroll
    for (int nb = 0; nb < 4; ++nb) sc[nb] = mfma16(qf[ks], kf[nb], sc[nb]);
  }

  int padv[4];
#pragma unroll
  for (int nb = 0; nb < 4; ++nb) padv[nb] = padp[kt + (nb << 4) + c];
  float sv[4][4];
#pragma unroll
  for (int nb = 0; nb < 4; ++nb) {
    bool pd = padv[nb] != 0;
    int key = kt + (nb << 4) + c;
#pragma unroll
    for (int r = 0; r < 4; ++r) {
      float s = sc[nb][r];
      if (CAUSAL && key > qrow_g + r) s = -1e30f;
      if (pd) s = -1e30f;
      sv[nb][r] = s;
    }
  }
  float tmax[4];
#pragma unroll
  for (int r = 0; r < 4; ++r)
    tmax[r] = fmaxf(fmaxf(sv[0][r], sv[1][r]), fmaxf(sv[2][r], sv[3][r]));
#pragma unroll
  for (int xm = 1; xm < 16; xm <<= 1)
#pragma unroll
    for (int r = 0; r < 4; ++r) tmax[r] = fmaxf(tmax[r], __shfl_xor(tmax[r], xm, 64));
  float al[4];
#pragma unroll
  for (int r = 0; r < 4; ++r) {
    float mn = fmaxf(m_r[r], tmax[r]);
    al[r] = __expf(m_r[r] - mn);
    m_r[r] = mn;
  }
  float ls[4] = {0.f, 0.f, 0.f, 0.f};
#pragma unroll
  for (int nb = 0; nb < 4; ++nb)
#pragma unroll
    for (int r = 0; r < 4; ++r) {
      float pp = __expf(sv[nb][r] - m_r[r]);
      sv[nb][r] = pp;
      ls[r] += pp;
    }
#pragma unroll
  for (int xm = 1; xm < 16; xm <<= 1)
#pragma unroll
    for (int r = 0; r < 4; ++r) ls[r] += __shfl_xor(ls[r], xm, 64);
#pragma unroll
  for (int r = 0; r < 4; ++r) l_r[r] = l_r[r] * al[r] + ls[r];
#pragma unroll
  for (int nb = 0; nb < 8; ++nb)
#pragma unroll
    for (int r = 0; r < 4; ++r) acc_o[nb][r] *= al[r];

#pragma unroll
  for (int nb = 0; nb < 4; ++nb)
#pragma unroll
    for (int r = 0; r < 4; ++r)
      p_w[(g * 4 + r) * 72 + (nb << 4) + c] = f2bf(sv[nb][r]);

#pragma unroll
  for (int ks = 0; ks < 2; ++ks) {
    bf16x8 pa = *(const bf16x8*)((const char*)p_w + c * 144 + ks * 64 + g * 16);
#pragma unroll
    for (int nb = 0; nb < 8; ++nb) {
      int n = (nb << 4) + c;
      int off = (n << 7) + (ks << 6) + (g << 4);
      bf16x8 vf = *(const bf16x8*)((const char*)v_lds + (off ^ ((n & 7) << 4)));
      acc_o[nb] = mfma16(pa, vf, acc_o[nb]);
    }
  }
}

// work map: j<256 -> (b=j>>5, qi=j&31, half0: tiles [0,T/2));
//           j>=256 -> (b, qi=31-(u&31), half1: tiles [T/2,T)). Pairs (j, j+256) balance.
__global__ __launch_bounds__(256) void flash_attn(
    const short* __restrict__ qp, const short* __restrict__ kp, const short* __restrict__ vt,
    const int* __restrict__ pad, float* __restrict__ partO, float* __restrict__ partML) {
  __shared__ short k_lds[2][64 * 128];
  __shared__ short v_lds[2][128 * 64];
  __shared__ short p_lds[4][16 * 72];
  const int tid = threadIdx.x, w = tid >> 6, lane = tid & 63;
  const int g = lane >> 4, c = lane & 15;
  const int j = blockIdx.x;
  int b, qi, half;
  if (j < 256) { b = j >> 5; qi = j & 31; half = 0; }
  else { int u = j - 256; b = u >> 5; qi = 31 - (u & 31); half = 1; }
  const int T = qi + 1;
  const int t0 = half ? (T >> 1) : 0;
  const int t1 = half ? T : (T >> 1);
  const int q0 = qi << 6;

  bf16x8 qf[4];
  {
    int token = (b << 11) + q0 + (w << 4) + c;
    const char* qrow = (const char*)qp + (size_t)token * 256;
#pragma unroll
    for (int s = 0; s < 4; ++s) qf[s] = *(const bf16x8*)(qrow + s * 64 + g * 16);
  }
  f32x4 acc_o[8];
#pragma unroll
  for (int i = 0; i < 8; ++i) acc_o[i] = (f32x4){0.f, 0.f, 0.f, 0.f};
  float m_r[4] = {-1e30f, -1e30f, -1e30f, -1e30f};
  float l_r[4] = {0.f, 0.f, 0.f, 0.f};

  const char* kb_base = (const char*)kp + (size_t)(b << 11) * 256;
  const char* vb_base = (const char*)vt + (size_t)b * 524288;
  const int* padp = pad + (b << 11);
  const int qrow_g = q0 + (w << 4) + (g << 2);

  if (t1 > t0) {
    stage_kv(k_lds[0], v_lds[0], kb_base, vb_base, t0, w, lane);
    __syncthreads();
    int cur = 0;
    for (int t = t0; t < t1; ++t) {
      if (t + 1 < t1)
        stage_kv(k_lds[cur ^ 1], v_lds[cur ^ 1], kb_base, vb_base, t + 1, w, lane);
      if (half && t == T - 1)
        attn_tile<true>(k_lds[cur], v_lds[cur], p_lds[w], qf, acc_o, m_r, l_r,
                        padp, t << 6, qrow_g, g, c);
      else
        attn_tile<false>(k_lds[cur], v_lds[cur], p_lds[w], qf, acc_o, m_r, l_r,
                         padp, t << 6, qrow_g, g, c);
      __syncthreads();
      cur ^= 1;
    }
  }

  float* pO = partO + (size_t)j * (64 * 128);
  float* pML = partML + (size_t)j * 128;
#pragma unroll
  for (int nb = 0; nb < 8; ++nb)
#pragma unroll
    for (int r = 0; r < 4; ++r)
      pO[(w * 16 + g * 4 + r) * 128 + (nb << 4) + c] = acc_o[nb][r];
  if (c == 0)
#pragma unroll
    for (int r = 0; r < 4; ++r) {
      pML[(w * 16 + g * 4 + r) * 2] = m_r[r];
      pML[(w * 16 + g * 4 + r) * 2 + 1] = l_r[r];
    }
}

// ---------------- combine: merge 2 partials, degenerate fixup ----------------
__global__ __launch_bounds__(256) void combine_kernel(
    const float* __restrict__ partO, const float* __restrict__ partML,
    const float* __restrict__ avgv, float* __restrict__ out) {
  int gid = blockIdx.x * 256 + threadIdx.x;   // 524288 float4s
  int row = gid >> 5;
  int d4 = gid & 31;
  int b = row >> 11, s = row & 2047;
  int qt = s >> 6, lr = s & 63;
  int wid1 = (b << 5) + qt;
  int wid2 = 256 + (b << 5) + (31 - qt);
  float m1 = partML[wid1 * 128 + lr * 2], l1 = partML[wid1 * 128 + lr * 2 + 1];
  float m2 = partML[wid2 * 128 + lr * 2], l2 = partML[wid2 * 128 + lr * 2 + 1];
  float m = fmaxf(m1, m2);
  f32x4 o;
  if (m < -1e8f) {
    o = *(const f32x4*)(avgv + (b << 7) + (d4 << 2));
  } else {
    float f1 = __expf(m1 - m), f2 = __expf(m2 - m);
    float inv = 1.0f / (l1 * f1 + l2 * f2);
    f32x4 o1 = *(const f32x4*)(partO + ((size_t)wid1 * 64 + lr) * 128 + (d4 << 2));
    f32x4 o2 = *(const f32x4*)(partO + ((size_t)wid2 * 64 + lr) * 128 + (d4 << 2));
#pragma unroll
    for (int k = 0; k < 4; ++k) o[k] = (o1[k] * f1 + o2[k] * f2) * inv;
  }
  *(f32x4*)(out + (size_t)row * 128 + (d4 << 2)) = o;
}

extern "C" void kernel_launch(void* const* d_in, const int* in_sizes, int n_in,
                              void* d_out, int out_size, void* d_ws, size_t ws_size,
                              hipStream_t stream) {
  const int*   pad   = (const int*)d_in[0];
  const float* query = (const float*)d_in[1];
  const float* key   = (const float*)d_in[2];
  const float* value = (const float*)d_in[3];
  const float* Wq    = (const float*)d_in[4];
  const float* bq    = (const float*)d_in[5];
  const float* Wk    = (const float*)d_in[6];
  const float* bk    = (const float*)d_in[7];
  const float* Wv    = (const float*)d_in[8];
  const float* bv    = (const float*)d_in[9];
  char* ws = (char*)d_ws;
  short* wt    = (short*)ws;                      // 768KB (fragment-ordered)
  short* qp    = (short*)(ws + 786432);           // 4MB
  short* kp    = (short*)(ws + 4980736);           // 4MB
  short* vt    = (short*)(ws + 9175040);          // 4MB  vT[8][128][2048]
  float* partO = (float*)(ws + 13369344);         // 512*64*128*4 = 16MB
  float* partML= (float*)(ws + 30146560);         // 512*64*2*4 = 256KB
  float* avgv  = (float*)(ws + 30408704);         // 4KB
  float* out   = (float*)d_out;

  prep_weights<<<dim3(192), dim3(256), 0, stream>>>(Wq, Wk, Wv, wt);
  proj_gemm<<<dim3(1536), dim3(64), 0, stream>>>(query, key, value, wt, bq, bk, bv, qp, kp, vt);
  avgv2_kernel<<<dim3(64), dim3(256), 0, stream>>>(vt, pad, bv, avgv);
  flash_attn<<<dim3(512), dim3(256), 0, stream>>>(qp, kp, vt, pad, partO, partML);
  combine_kernel<<<dim3(2048), dim3(256), 0, stream>>>(partO, partML, avgv, out);
}

// Round 4
// 99.460 us; speedup vs baseline: 1.0668x; 1.0668x over previous
//
#include <hip/hip_runtime.h>
#include <hip/hip_bf16.h>

#define SEQ 2048
#define EMB 1024
#define DH  128
#define QSCALE 0.08838834764831845f  // 1/sqrt(128)

typedef __attribute__((ext_vector_type(4))) float f32x4;
typedef __attribute__((ext_vector_type(8))) short bf16x8;
typedef __attribute__((ext_vector_type(4))) short bf16x4;

__device__ __forceinline__ short f2bf(float f) {
  unsigned u = __builtin_bit_cast(unsigned, f);
  u += 0x7fffu + ((u >> 16) & 1u);   // RNE
  return (short)(u >> 16);
}

__device__ __forceinline__ float bf2f(short s) {
  unsigned u = ((unsigned)(unsigned short)s) << 16;
  return __builtin_bit_cast(float, u);
}

__device__ __forceinline__ f32x4 mfma16(bf16x8 a, bf16x8 b, f32x4 c) {
  return __builtin_amdgcn_mfma_f32_16x16x32_bf16(a, b, c, 0, 0, 0);
}

// async global->LDS, 16B per lane; lds_base must be wave-uniform (HW adds lane*16)
__device__ __forceinline__ void gl_lds16(void* lds_base, const void* gsrc) {
  __builtin_amdgcn_global_load_lds(
      (const __attribute__((address_space(1))) void*)gsrc,
      (__attribute__((address_space(3))) void*)lds_base, 16, 0, 0);
}

// ---------------- weight prep ----------------
// W[E][128] f32 -> wt[p][kk][nb][lane][8] bf16 (exact B-fragment order for
// mfma_f32_16x16x32_bf16: lane l holds B[k = kk*32 + (l>>4)*8 + j][n = nb*16 + (l&15)]).
__global__ void prep_weights(const float* __restrict__ Wq, const float* __restrict__ Wk,
                             const float* __restrict__ Wv, short* __restrict__ wt) {
  int gid = blockIdx.x * 256 + threadIdx.x;
  int lane = gid & 63, c = lane & 15, g = (lane >> 4) & 3;
  int nb = (gid >> 6) & 7;
  int kk = (gid >> 9) & 31;
  int p = gid >> 14;
  const float* W = (p == 0) ? Wq : ((p == 1) ? Wk : Wv);
  bf16x8 v;
#pragma unroll
  for (int j = 0; j < 8; ++j)
    v[j] = f2bf(W[(kk * 32 + g * 8 + j) * DH + nb * 16 + c]);
  *(bf16x8*)(&wt[(size_t)gid * 8]) = v;
}

// ---------------- projection GEMM: per-wave LDS pipeline + K-rotation ---------------
// Round-2 chassis (counted vmcnt, zero barriers) with ONE change: each block starts
// its K loop at k0 = (bid*5)&31 and walks kk = (k0+t)%32. Rationale: X rows are 4KB;
// without rotation every block reads the SAME intra-row offset simultaneously ->
// chip-wide requests concentrate on 1/32 of the channel/bank interleave space
// (~1.2 TB/s wall in rounds 0-3). Rotation spreads concurrent requests across all
// 32 offsets. Accumulation order over K is irrelevant (f32 acc).
__global__ __launch_bounds__(64, 2) void proj_gemm(
    const float* __restrict__ Xq, const float* __restrict__ Xk, const float* __restrict__ Xv,
    const short* __restrict__ wt,
    const float* __restrict__ bq, const float* __restrict__ bk, const float* __restrict__ bv,
    short* __restrict__ qp, short* __restrict__ kp, short* __restrict__ vt) {
  __shared__ char abuf[2][4096];   // 32 rows x 128B (one K-step of 32 f32)
  __shared__ char wbuf[2][8192];   // 8 fragment chunks x 1KB

  const int lane = threadIdx.x;
  const int g = lane >> 4, c = lane & 15;
  const int wid = blockIdx.x;
  const int p = wid >> 9, mb = wid & 511;
  const int row0 = mb << 5;                         // 32-row tile
  const int k0 = (wid * 5) & 31;                    // per-block K phase
  const float* X    = (p == 0) ? Xq : ((p == 1) ? Xk : Xv);
  const float* bias = (p == 0) ? bq : ((p == 1) ? bk : bv);
  const char* Xb  = (const char*)X;
  const char* Wtb = (const char*)wt + (size_t)p * 262144;

  f32x4 acc[2][8];
#pragma unroll
  for (int rb = 0; rb < 2; ++rb)
#pragma unroll
    for (int nb = 0; nb < 8; ++nb) acc[rb][nb] = (f32x4){0.f, 0.f, 0.f, 0.f};

  // stage: 12 x 1KB global_load_lds. A source pre-XOR-swizzled (swizzle source,
  // linear LDS dest, swizzle on read). W already fragment-ordered -> linear both sides.
  // kk here is the PHYSICAL K index (already rotated).
  auto stage = [&](char* ab, char* wb, int kk) {
#pragma unroll
    for (int i = 0; i < 4; ++i) {
      int q = i * 1024 + lane * 16;
      int lg = q ^ (((q >> 7) & 7) << 4);
      gl_lds16(ab + i * 1024,
               Xb + (size_t)(row0 + (lg >> 7)) * 4096 + kk * 128 + (lg & 127));
    }
#pragma unroll
    for (int i = 0; i < 8; ++i)
      gl_lds16(wb + i * 1024, Wtb + (size_t)kk * 8192 + i * 1024 + lane * 16);
  };

  auto compute = [&](const char* ab, const char* wb) {
    bf16x8 wfr[8];
#pragma unroll
    for (int nb = 0; nb < 8; ++nb)
      wfr[nb] = *(const bf16x8*)(wb + nb * 1024 + lane * 16);
#pragma unroll
    for (int rb = 0; rb < 2; ++rb) {
      int r = (rb << 4) + c;
      int ad = ((r << 7) + (g << 5)) ^ ((r & 7) << 4);
      f32x4 lo = *(const f32x4*)(ab + ad);
      f32x4 hi = *(const f32x4*)(ab + (ad ^ 16));
      bf16x8 a;
#pragma unroll
      for (int j = 0; j < 4; ++j) { a[j] = f2bf(lo[j]); a[4 + j] = f2bf(hi[j]); }
#pragma unroll
      for (int nb = 0; nb < 8; ++nb) acc[rb][nb] = mfma16(a, wfr[nb], acc[rb][nb]);
    }
  };

  auto kmap = [&](int t) { int k = k0 + t; return k & 31; };

  stage(abuf[0], wbuf[0], kmap(0));
#pragma unroll 1
  for (int kk = 0; kk < 32; kk += 2) {
    stage(abuf[1], wbuf[1], kmap(kk + 1));           // kk <= 30, always valid
    asm volatile("s_waitcnt vmcnt(12)" ::: "memory");  // buf0's 12 retired, buf1 in flight
    compute(abuf[0], wbuf[0]);
    __builtin_amdgcn_sched_barrier(0);               // keep WAR order: reads(buf0) < writes(buf0)
    if (kk + 2 < 32) {
      stage(abuf[0], wbuf[0], kmap(kk + 2));
      asm volatile("s_waitcnt vmcnt(12)" ::: "memory");  // buf1's retired, buf0 in flight
    } else {
      asm volatile("s_waitcnt vmcnt(0)" ::: "memory");
    }
    compute(abuf[1], wbuf[1]);
    __builtin_amdgcn_sched_barrier(0);
  }

  // epilogue: C/D layout col = c, row = g*4 + reg (within each 16-row sub-tile)
  float bvals[8];
#pragma unroll
  for (int nb = 0; nb < 8; ++nb) bvals[nb] = bias[nb * 16 + c];

  if (p < 2) {   // q (scaled) / k, row-major [token][128] bf16
    short* outp = (p == 0) ? qp : kp;
    float sc = (p == 0) ? QSCALE : 1.0f;
#pragma unroll
    for (int rb = 0; rb < 2; ++rb)
#pragma unroll
      for (int r = 0; r < 4; ++r) {
        int token = row0 + (rb << 4) + g * 4 + r;
#pragma unroll
        for (int nb = 0; nb < 8; ++nb)
          outp[token * 128 + nb * 16 + c] = f2bf((acc[rb][nb][r] + bvals[nb]) * sc);
      }
  } else {       // v transposed: vT[b][d][s] bf16
#pragma unroll
    for (int rb = 0; rb < 2; ++rb) {
      int tok0 = row0 + (rb << 4) + g * 4;
      int b_ = tok0 >> 11, s_ = tok0 & 2047;
#pragma unroll
      for (int nb = 0; nb < 8; ++nb) {
        int col = nb * 16 + c;
        bf16x4 v4;
#pragma unroll
        for (int r = 0; r < 4; ++r) v4[r] = f2bf(acc[rb][nb][r] + bvals[nb]);
        *(bf16x4*)(&vt[((size_t)(b_ * 128 + col)) * 2048 + s_]) = v4;
      }
    }
  }
}

// ---------------- avgV from projected V (degenerate-row fixup) ----------------
// avgv[b][d] = mean over padded s of vt[b][d][s]  (vt already includes bias)
__global__ __launch_bounds__(256) void avgv2_kernel(
    const short* __restrict__ vt, const int* __restrict__ pad,
    const float* __restrict__ bvv, float* __restrict__ avgv) {
  int b = blockIdx.x >> 3, dg = blockIdx.x & 7;
  int t = threadIdx.x, doff = t >> 4, sl = t & 15;
  int d = dg * 16 + doff;
  const short* vrow = vt + ((size_t)(b * 128 + d)) * 2048 + sl * 128;
  const int* prow = pad + (b << 11) + sl * 128;
  float sum = 0.f;
  int cnt = 0;
  for (int i = 0; i < 16; ++i) {
    bf16x8 v8 = *(const bf16x8*)(vrow + i * 8);
#pragma unroll
    for (int j = 0; j < 8; ++j) {
      int pd = prow[i * 8 + j];
      cnt += (pd != 0);
      if (pd) sum += bf2f(v8[j]);
    }
  }
#pragma unroll
  for (int xm = 1; xm < 16; xm <<= 1) {
    sum += __shfl_xor(sum, xm, 64);
    cnt += __shfl_xor(cnt, xm, 64);
  }
  if (sl == 0) avgv[(b << 7) + d] = (cnt > 0) ? (sum / (float)cnt) : 0.f;
  (void)bvv;
}

// ---------------- flash attention (causal, split-KV x2, double-buffered) ----------------
__device__ __forceinline__ void stage_kv(short* kb, short* vb,
                                         const char* kb_base, const char* vb_base,
                                         int kt, int w, int lane) {
#pragma unroll
  for (int ch = w; ch < 16; ch += 4) {   // K tile [key][d], swizzled 256B rows
    int phys = ch * 1024 + lane * 16;
    int lg = phys ^ (((phys >> 8) & 7) << 4);
    gl_lds16((char*)kb + ch * 1024,
             kb_base + (size_t)(kt * 64 + (lg >> 8)) * 256 + (lg & 255));
  }
#pragma unroll
  for (int ch = w; ch < 16; ch += 4) {   // V^T tile [d][key], swizzled 128B rows
    int phys = ch * 1024 + lane * 16;
    int lg = phys ^ (((phys >> 7) & 7) << 4);
    gl_lds16((char*)vb + ch * 1024,
             vb_base + (size_t)(lg >> 7) * 4096 + kt * 128 + (lg & 127));
  }
}

template <bool CAUSAL>
__device__ __forceinline__ void attn_tile(
    const short* __restrict__ k_lds, const short* __restrict__ v_lds, short* __restrict__ p_w,
    const bf16x8 (&qf)[4], f32x4 (&acc_o)[8], float (&m_r)[4], float (&l_r)[4],
    const int* __restrict__ padp, int kt, int qrow_g, int g, int c) {
  f32x4 sc[4];
#pragma unroll
  for (int nb = 0; nb < 4; ++nb) sc[nb] = (f32x4){0.f, 0.f, 0.f, 0.f};
#pragma unroll
  for (int ks = 0; ks < 4; ++ks) {
    bf16x8 kf[4];
#pragma unroll
    for (int nb = 0; nb < 4; ++nb) {
      int n = (nb << 4) + c;
      int off = (n << 8) + (ks << 6) + (g << 4);
      kf[nb] = *(const bf16x8*)((const char*)k_lds + (off ^ ((n & 7) << 4)));
    }
#pragma unroll
    for (int nb = 0; nb < 4; ++nb) sc[nb] = mfma16(qf[ks], kf[nb], sc[nb]);
  }

  int padv[4];
#pragma unroll
  for (int nb = 0; nb < 4; ++nb) padv[nb] = padp[kt + (nb << 4) + c];
  float sv[4][4];
#pragma unroll
  for (int nb = 0; nb < 4; ++nb) {
    bool pd = padv[nb] != 0;
    int key = kt + (nb << 4) + c;
#pragma unroll
    for (int r = 0; r < 4; ++r) {
      float s = sc[nb][r];
      if (CAUSAL && key > qrow_g + r) s = -1e30f;
      if (pd) s = -1e30f;
      sv[nb][r] = s;
    }
  }
  float tmax[4];
#pragma unroll
  for (int r = 0; r < 4; ++r)
    tmax[r] = fmaxf(fmaxf(sv[0][r], sv[1][r]), fmaxf(sv[2][r], sv[3][r]));
#pragma unroll
  for (int xm = 1; xm < 16; xm <<= 1)
#pragma unroll
    for (int r = 0; r < 4; ++r) tmax[r] = fmaxf(tmax[r], __shfl_xor(tmax[r], xm, 64));
  float al[4];
#pragma unroll
  for (int r = 0; r < 4; ++r) {
    float mn = fmaxf(m_r[r], tmax[r]);
    al[r] = __expf(m_r[r] - mn);
    m_r[r] = mn;
  }
  float ls[4] = {0.f, 0.f, 0.f, 0.f};
#pragma unroll
  for (int nb = 0; nb < 4; ++nb)
#pragma unroll
    for (int r = 0; r < 4; ++r) {
      float pp = __expf(sv[nb][r] - m_r[r]);
      sv[nb][r] = pp;
      ls[r] += pp;
    }
#pragma unroll
  for (int xm = 1; xm < 16; xm <<= 1)
#pragma unroll
    for (int r = 0; r < 4; ++r) ls[r] += __shfl_xor(ls[r], xm, 64);
#pragma unroll
  for (int r = 0; r < 4; ++r) l_r[r] = l_r[r] * al[r] + ls[r];
#pragma unroll
  for (int nb = 0; nb < 8; ++nb)
#pragma unroll
    for (int r = 0; r < 4; ++r) acc_o[nb][r] *= al[r];

#pragma unroll
  for (int nb = 0; nb < 4; ++nb)
#pragma unroll
    for (int r = 0; r < 4; ++r)
      p_w[(g * 4 + r) * 72 + (nb << 4) + c] = f2bf(sv[nb][r]);

#pragma unroll
  for (int ks = 0; ks < 2; ++ks) {
    bf16x8 pa = *(const bf16x8*)((const char*)p_w + c * 144 + ks * 64 + g * 16);
#pragma unroll
    for (int nb = 0; nb < 8; ++nb) {
      int n = (nb << 4) + c;
      int off = (n << 7) + (ks << 6) + (g << 4);
      bf16x8 vf = *(const bf16x8*)((const char*)v_lds + (off ^ ((n & 7) << 4)));
      acc_o[nb] = mfma16(pa, vf, acc_o[nb]);
    }
  }
}

// work map: j<256 -> (b=j>>5, qi=j&31, half0: tiles [0,T/2));
//           j>=256 -> (b, qi=31-(u&31), half1: tiles [T/2,T)). Pairs (j, j+256) balance.
__global__ __launch_bounds__(256) void flash_attn(
    const short* __restrict__ qp, const short* __restrict__ kp, const short* __restrict__ vt,
    const int* __restrict__ pad, float* __restrict__ partO, float* __restrict__ partML) {
  __shared__ short k_lds[2][64 * 128];
  __shared__ short v_lds[2][128 * 64];
  __shared__ short p_lds[4][16 * 72];
  const int tid = threadIdx.x, w = tid >> 6, lane = tid & 63;
  const int g = lane >> 4, c = lane & 15;
  const int j = blockIdx.x;
  int b, qi, half;
  if (j < 256) { b = j >> 5; qi = j & 31; half = 0; }
  else { int u = j - 256; b = u >> 5; qi = 31 - (u & 31); half = 1; }
  const int T = qi + 1;
  const int t0 = half ? (T >> 1) : 0;
  const int t1 = half ? T : (T >> 1);
  const int q0 = qi << 6;

  bf16x8 qf[4];
  {
    int token = (b << 11) + q0 + (w << 4) + c;
    const char* qrow = (const char*)qp + (size_t)token * 256;
#pragma unroll
    for (int s = 0; s < 4; ++s) qf[s] = *(const bf16x8*)(qrow + s * 64 + g * 16);
  }
  f32x4 acc_o[8];
#pragma unroll
  for (int i = 0; i < 8; ++i) acc_o[i] = (f32x4){0.f, 0.f, 0.f, 0.f};
  float m_r[4] = {-1e30f, -1e30f, -1e30f, -1e30f};
  float l_r[4] = {0.f, 0.f, 0.f, 0.f};

  const char* kb_base = (const char*)kp + (size_t)(b << 11) * 256;
  const char* vb_base = (const char*)vt + (size_t)b * 524288;
  const int* padp = pad + (b << 11);
  const int qrow_g = q0 + (w << 4) + (g << 2);

  if (t1 > t0) {
    stage_kv(k_lds[0], v_lds[0], kb_base, vb_base, t0, w, lane);
    __syncthreads();
    int cur = 0;
    for (int t = t0; t < t1; ++t) {
      if (t + 1 < t1)
        stage_kv(k_lds[cur ^ 1], v_lds[cur ^ 1], kb_base, vb_base, t + 1, w, lane);
      if (half && t == T - 1)
        attn_tile<true>(k_lds[cur], v_lds[cur], p_lds[w], qf, acc_o, m_r, l_r,
                        padp, t << 6, qrow_g, g, c);
      else
        attn_tile<false>(k_lds[cur], v_lds[cur], p_lds[w], qf, acc_o, m_r, l_r,
                         padp, t << 6, qrow_g, g, c);
      __syncthreads();
      cur ^= 1;
    }
  }

  float* pO = partO + (size_t)j * (64 * 128);
  float* pML = partML + (size_t)j * 128;
#pragma unroll
  for (int nb = 0; nb < 8; ++nb)
#pragma unroll
    for (int r = 0; r < 4; ++r)
      pO[(w * 16 + g * 4 + r) * 128 + (nb << 4) + c] = acc_o[nb][r];
  if (c == 0)
#pragma unroll
    for (int r = 0; r < 4; ++r) {
      pML[(w * 16 + g * 4 + r) * 2] = m_r[r];
      pML[(w * 16 + g * 4 + r) * 2 + 1] = l_r[r];
    }
}

// ---------------- combine: merge 2 partials, degenerate fixup ----------------
__global__ __launch_bounds__(256) void combine_kernel(
    const float* __restrict__ partO, const float* __restrict__ partML,
    const float* __restrict__ avgv, float* __restrict__ out) {
  int gid = blockIdx.x * 256 + threadIdx.x;   // 524288 float4s
  int row = gid >> 5;
  int d4 = gid & 31;
  int b = row >> 11, s = row & 2047;
  int qt = s >> 6, lr = s & 63;
  int wid1 = (b << 5) + qt;
  int wid2 = 256 + (b << 5) + (31 - qt);
  float m1 = partML[wid1 * 128 + lr * 2], l1 = partML[wid1 * 128 + lr * 2 + 1];
  float m2 = partML[wid2 * 128 + lr * 2], l2 = partML[wid2 * 128 + lr * 2 + 1];
  float m = fmaxf(m1, m2);
  f32x4 o;
  if (m < -1e8f) {
    o = *(const f32x4*)(avgv + (b << 7) + (d4 << 2));
  } else {
    float f1 = __expf(m1 - m), f2 = __expf(m2 - m);
    float inv = 1.0f / (l1 * f1 + l2 * f2);
    f32x4 o1 = *(const f32x4*)(partO + ((size_t)wid1 * 64 + lr) * 128 + (d4 << 2));
    f32x4 o2 = *(const f32x4*)(partO + ((size_t)wid2 * 64 + lr) * 128 + (d4 << 2));
#pragma unroll
    for (int k = 0; k < 4; ++k) o[k] = (o1[k] * f1 + o2[k] * f2) * inv;
  }
  *(f32x4*)(out + (size_t)row * 128 + (d4 << 2)) = o;
}

extern "C" void kernel_launch(void* const* d_in, const int* in_sizes, int n_in,
                              void* d_out, int out_size, void* d_ws, size_t ws_size,
                              hipStream_t stream) {
  const int*   pad   = (const int*)d_in[0];
  const float* query = (const float*)d_in[1];
  const float* key   = (const float*)d_in[2];
  const float* value = (const float*)d_in[3];
  const float* Wq    = (const float*)d_in[4];
  const float* bq    = (const float*)d_in[5];
  const float* Wk    = (const float*)d_in[6];
  const float* bk    = (const float*)d_in[7];
  const float* Wv    = (const float*)d_in[8];
  const float* bv    = (const float*)d_in[9];
  char* ws = (char*)d_ws;
  short* wt    = (short*)ws;                      // 768KB (fragment-ordered)
  short* qp    = (short*)(ws + 786432);           // 4MB
  short* kp    = (short*)(ws + 4980736);          // 4MB
  short* vt    = (short*)(ws + 9175040);          // 4MB  vT[8][128][2048]
  float* partO = (float*)(ws + 13369344);         // 512*64*128*4 = 16MB
  float* partML= (float*)(ws + 30146560);         // 512*64*2*4 = 256KB
  float* avgv  = (float*)(ws + 30408704);         // 4KB
  float* out   = (float*)d_out;

  prep_weights<<<dim3(192), dim3(256), 0, stream>>>(Wq, Wk, Wv, wt);
  proj_gemm<<<dim3(1536), dim3(64), 0, stream>>>(query, key, value, wt, bq, bk, bv, qp, kp, vt);
  avgv2_kernel<<<dim3(64), dim3(256), 0, stream>>>(vt, pad, bv, avgv);
  flash_attn<<<dim3(512), dim3(256), 0, stream>>>(qp, kp, vt, pad, partO, partML);
  combine_kernel<<<dim3(2048), dim3(256), 0, stream>>>(partO, partML, avgv, out);
}

// Round 5
// 96.811 us; speedup vs baseline: 1.0960x; 1.0274x over previous
//
#include <hip/hip_runtime.h>
#include <hip/hip_bf16.h>

#define SEQ 2048
#define EMB 1024
#define DH  128
#define QSCALE 0.08838834764831845f  // 1/sqrt(128)

typedef __attribute__((ext_vector_type(4))) float f32x4;
typedef __attribute__((ext_vector_type(8))) short bf16x8;
typedef __attribute__((ext_vector_type(4))) short bf16x4;

__device__ __forceinline__ short f2bf(float f) {
  unsigned u = __builtin_bit_cast(unsigned, f);
  u += 0x7fffu + ((u >> 16) & 1u);   // RNE
  return (short)(u >> 16);
}

__device__ __forceinline__ float bf2f(short s) {
  unsigned u = ((unsigned)(unsigned short)s) << 16;
  return __builtin_bit_cast(float, u);
}

__device__ __forceinline__ f32x4 mfma16(bf16x8 a, bf16x8 b, f32x4 c) {
  return __builtin_amdgcn_mfma_f32_16x16x32_bf16(a, b, c, 0, 0, 0);
}

// async global->LDS, 16B per lane; lds_base must be wave-uniform (HW adds lane*16)
__device__ __forceinline__ void gl_lds16(void* lds_base, const void* gsrc) {
  __builtin_amdgcn_global_load_lds(
      (const __attribute__((address_space(1))) void*)gsrc,
      (__attribute__((address_space(3))) void*)lds_base, 16, 0, 0);
}

// ---------------- weight prep ----------------
// W[E][128] f32 -> wt[p][kk][nb][lane][8] bf16 (exact B-fragment order for
// mfma_f32_16x16x32_bf16: lane l holds B[k = kk*32 + (l>>4)*8 + j][n = nb*16 + (l&15)]).
__global__ void prep_weights(const float* __restrict__ Wq, const float* __restrict__ Wk,
                             const float* __restrict__ Wv, short* __restrict__ wt) {
  int gid = blockIdx.x * 256 + threadIdx.x;
  int lane = gid & 63, c = lane & 15, g = (lane >> 4) & 3;
  int nb = (gid >> 6) & 7;
  int kk = (gid >> 9) & 31;
  int p = gid >> 14;
  const float* W = (p == 0) ? Wq : ((p == 1) ? Wk : Wv);
  bf16x8 v;
#pragma unroll
  for (int j = 0; j < 8; ++j)
    v[j] = f2bf(W[(kk * 32 + g * 8 + j) * DH + nb * 16 + c]);
  *(bf16x8*)(&wt[(size_t)gid * 8]) = v;
}

// ---------------- projection GEMM: 4-wave T3/T4 pipeline ----------------
// Theory: per-wave gl_lds throughput is ~2 B/cy (latency-bound constant, matches
// m97-class kernels). Rounds 1-4 had only 4.7-6 waves/CU -> ~1.2 TB/s wall.
// Fix: 256-thread blocks (4 waves), 768 blocks = EXACTLY 3 blocks/CU = 12 waves/CU,
// counted vmcnt(4) + RAW s_barrier (no vmcnt(0) drain, unlike __syncthreads), 3-buffer
// LDS ring, stage-1-ahead. Each wave stages 4 KB/step (2 A + 2 W chunks of 1 KB).
// WAR safety: buf[t%3] next written for tile t+3 at iter t+2, which all waves reach
// only after barrier(t+1), which follows every wave's compute(t) reads.
__global__ __launch_bounds__(256, 3) void proj_gemm(
    const float* __restrict__ Xq, const float* __restrict__ Xk, const float* __restrict__ Xv,
    const short* __restrict__ wt,
    const float* __restrict__ bq, const float* __restrict__ bk, const float* __restrict__ bv,
    short* __restrict__ qp, short* __restrict__ kp, short* __restrict__ vt) {
  __shared__ char abuf[3][8192];   // 64 rows x 128B per buffer
  __shared__ char wbuf[3][8192];   // 8 fragment chunks x 1KB per buffer

  const int tid = threadIdx.x;
  const int w = tid >> 6, lane = tid & 63;
  const int g = lane >> 4, c = lane & 15;
  const int bid = blockIdx.x;
  const int p = bid >> 8, mb = bid & 255;
  const int row0 = mb << 6;                         // 64-row tile
  const int k0 = (bid * 5) & 31;                    // per-block K phase (free de-phasing)
  const float* X    = (p == 0) ? Xq : ((p == 1) ? Xk : Xv);
  const float* bias = (p == 0) ? bq : ((p == 1) ? bk : bv);
  const char* Xb  = (const char*)X;
  const char* Wtb = (const char*)wt + (size_t)p * 262144;

  f32x4 acc[8];
#pragma unroll
  for (int nb = 0; nb < 8; ++nb) acc[nb] = (f32x4){0.f, 0.f, 0.f, 0.f};

  // stage: this wave's 4 x 1KB share (A chunks {w,w+4} of 8, W chunks {w,w+4} of 8).
  // A source pre-XOR-swizzled (linear LDS dest, swizzle applied again on read).
  auto stage = [&](int buf, int kk) {
#pragma unroll
    for (int i = 0; i < 2; ++i) {
      int ch = w + i * 4;
      int phys = ch * 1024 + lane * 16;
      int lg = phys ^ (((phys >> 7) & 7) << 4);
      gl_lds16(abuf[buf] + ch * 1024,
               Xb + (size_t)(row0 + (lg >> 7)) * 4096 + kk * 128 + (lg & 127));
    }
#pragma unroll
    for (int i = 0; i < 2; ++i) {
      int ch = w + i * 4;
      gl_lds16(wbuf[buf] + ch * 1024,
               Wtb + (size_t)kk * 8192 + ch * 1024 + lane * 16);
    }
  };

  // compute: wave w owns block-rows w*16..w*16+15 -> 1 A fragment, 8 MFMAs.
  auto compute = [&](int buf) {
    const char* ab = abuf[buf];
    const char* wb = wbuf[buf];
    bf16x8 wfr[8];
#pragma unroll
    for (int nb = 0; nb < 8; ++nb)
      wfr[nb] = *(const bf16x8*)(wb + nb * 1024 + lane * 16);
    int r = (w << 4) + c;
    int ad = (r << 7) + ((g << 5) ^ ((r & 7) << 4));
    f32x4 lo = *(const f32x4*)(ab + ad);
    f32x4 hi = *(const f32x4*)(ab + (ad ^ 16));
    bf16x8 a;
#pragma unroll
    for (int j = 0; j < 4; ++j) { a[j] = f2bf(lo[j]); a[4 + j] = f2bf(hi[j]); }
#pragma unroll
    for (int nb = 0; nb < 8; ++nb) acc[nb] = mfma16(a, wfr[nb], acc[nb]);
  };

  stage(0, k0);
  int bufc = 0;
#pragma unroll 1
  for (int t = 0; t < 32; ++t) {
    int nbuf = (bufc == 2) ? 0 : bufc + 1;
    if (t + 1 < 32) {
      stage(nbuf, (k0 + t + 1) & 31);
      asm volatile("s_waitcnt vmcnt(4)" ::: "memory");  // retire step t's 4; keep t+1's in flight
    } else {
      asm volatile("s_waitcnt vmcnt(0)" ::: "memory");
    }
    __builtin_amdgcn_s_barrier();                       // raw barrier: no vmcnt(0) drain
    __builtin_amdgcn_sched_barrier(0);
    compute(bufc);
    bufc = nbuf;
  }

  // epilogue: C/D layout col = c, row = g*4 + reg (within this wave's 16-row tile)
  float bvals[8];
#pragma unroll
  for (int nb = 0; nb < 8; ++nb) bvals[nb] = bias[nb * 16 + c];

  if (p < 2) {   // q (scaled) / k, row-major [token][128] bf16
    short* outp = (p == 0) ? qp : kp;
    float sc = (p == 0) ? QSCALE : 1.0f;
#pragma unroll
    for (int r = 0; r < 4; ++r) {
      int token = row0 + (w << 4) + g * 4 + r;
#pragma unroll
      for (int nb = 0; nb < 8; ++nb)
        outp[token * 128 + nb * 16 + c] = f2bf((acc[nb][r] + bvals[nb]) * sc);
    }
  } else {       // v transposed: vT[b][d][s] bf16
    int tok0 = row0 + (w << 4) + g * 4;
    int b_ = tok0 >> 11, s_ = tok0 & 2047;
#pragma unroll
    for (int nb = 0; nb < 8; ++nb) {
      int col = nb * 16 + c;
      bf16x4 v4;
#pragma unroll
      for (int r = 0; r < 4; ++r) v4[r] = f2bf(acc[nb][r] + bvals[nb]);
      *(bf16x4*)(&vt[((size_t)(b_ * 128 + col)) * 2048 + s_]) = v4;
    }
  }
}

// ---------------- avgV from projected V (degenerate-row fixup) ----------------
// avgv[b][d] = mean over padded s of vt[b][d][s]  (vt already includes bias)
__global__ __launch_bounds__(256) void avgv2_kernel(
    const short* __restrict__ vt, const int* __restrict__ pad,
    const float* __restrict__ bvv, float* __restrict__ avgv) {
  int b = blockIdx.x >> 3, dg = blockIdx.x & 7;
  int t = threadIdx.x, doff = t >> 4, sl = t & 15;
  int d = dg * 16 + doff;
  const short* vrow = vt + ((size_t)(b * 128 + d)) * 2048 + sl * 128;
  const int* prow = pad + (b << 11) + sl * 128;
  float sum = 0.f;
  int cnt = 0;
  for (int i = 0; i < 16; ++i) {
    bf16x8 v8 = *(const bf16x8*)(vrow + i * 8);
#pragma unroll
    for (int j = 0; j < 8; ++j) {
      int pd = prow[i * 8 + j];
      cnt += (pd != 0);
      if (pd) sum += bf2f(v8[j]);
    }
  }
#pragma unroll
  for (int xm = 1; xm < 16; xm <<= 1) {
    sum += __shfl_xor(sum, xm, 64);
    cnt += __shfl_xor(cnt, xm, 64);
  }
  if (sl == 0) avgv[(b << 7) + d] = (cnt > 0) ? (sum / (float)cnt) : 0.f;
  (void)bvv;
}

// ---------------- flash attention (causal, split-KV x2, double-buffered) ----------------
__device__ __forceinline__ void stage_kv(short* kb, short* vb,
                                         const char* kb_base, const char* vb_base,
                                         int kt, int w, int lane) {
#pragma unroll
  for (int ch = w; ch < 16; ch += 4) {   // K tile [key][d], swizzled 256B rows
    int phys = ch * 1024 + lane * 16;
    int lg = phys ^ (((phys >> 8) & 7) << 4);
    gl_lds16((char*)kb + ch * 1024,
             kb_base + (size_t)(kt * 64 + (lg >> 8)) * 256 + (lg & 255));
  }
#pragma unroll
  for (int ch = w; ch < 16; ch += 4) {   // V^T tile [d][key], swizzled 128B rows
    int phys = ch * 1024 + lane * 16;
    int lg = phys ^ (((phys >> 7) & 7) << 4);
    gl_lds16((char*)vb + ch * 1024,
             vb_base + (size_t)(lg >> 7) * 4096 + kt * 128 + (lg & 127));
  }
}

template <bool CAUSAL>
__device__ __forceinline__ void attn_tile(
    const short* __restrict__ k_lds, const short* __restrict__ v_lds, short* __restrict__ p_w,
    const bf16x8 (&qf)[4], f32x4 (&acc_o)[8], float (&m_r)[4], float (&l_r)[4],
    const int* __restrict__ padp, int kt, int qrow_g, int g, int c) {
  f32x4 sc[4];
#pragma unroll
  for (int nb = 0; nb < 4; ++nb) sc[nb] = (f32x4){0.f, 0.f, 0.f, 0.f};
#pragma unroll
  for (int ks = 0; ks < 4; ++ks) {
    bf16x8 kf[4];
#pragma unroll
    for (int nb = 0; nb < 4; ++nb) {
      int n = (nb << 4) + c;
      int off = (n << 8) + (ks << 6) + (g << 4);
      kf[nb] = *(const bf16x8*)((const char*)k_lds + (off ^ ((n & 7) << 4)));
    }
#pragma unroll
    for (int nb = 0; nb < 4; ++nb) sc[nb] = mfma16(qf[ks], kf[nb], sc[nb]);
  }

  int padv[4];
#pragma unroll
  for (int nb = 0; nb < 4; ++nb) padv[nb] = padp[kt + (nb << 4) + c];
  float sv[4][4];
#pragma unroll
  for (int nb = 0; nb < 4; ++nb) {
    bool pd = padv[nb] != 0;
    int key = kt + (nb << 4) + c;
#pragma unroll
    for (int r = 0; r < 4; ++r) {
      float s = sc[nb][r];
      if (CAUSAL && key > qrow_g + r) s = -1e30f;
      if (pd) s = -1e30f;
      sv[nb][r] = s;
    }
  }
  float tmax[4];
#pragma unroll
  for (int r = 0; r < 4; ++r)
    tmax[r] = fmaxf(fmaxf(sv[0][r], sv[1][r]), fmaxf(sv[2][r], sv[3][r]));
#pragma unroll
  for (int xm = 1; xm < 16; xm <<= 1)
#pragma unroll
    for (int r = 0; r < 4; ++r) tmax[r] = fmaxf(tmax[r], __shfl_xor(tmax[r], xm, 64));
  float al[4];
#pragma unroll
  for (int r = 0; r < 4; ++r) {
    float mn = fmaxf(m_r[r], tmax[r]);
    al[r] = __expf(m_r[r] - mn);
    m_r[r] = mn;
  }
  float ls[4] = {0.f, 0.f, 0.f, 0.f};
#pragma unroll
  for (int nb = 0; nb < 4; ++nb)
#pragma unroll
    for (int r = 0; r < 4; ++r) {
      float pp = __expf(sv[nb][r] - m_r[r]);
      sv[nb][r] = pp;
      ls[r] += pp;
    }
#pragma unroll
  for (int xm = 1; xm < 16; xm <<= 1)
#pragma unroll
    for (int r = 0; r < 4; ++r) ls[r] += __shfl_xor(ls[r], xm, 64);
#pragma unroll
  for (int r = 0; r < 4; ++r) l_r[r] = l_r[r] * al[r] + ls[r];
#pragma unroll
  for (int nb = 0; nb < 8; ++nb)
#pragma unroll
    for (int r = 0; r < 4; ++r) acc_o[nb][r] *= al[r];

#pragma unroll
  for (int nb = 0; nb < 4; ++nb)
#pragma unroll
    for (int r = 0; r < 4; ++r)
      p_w[(g * 4 + r) * 72 + (nb << 4) + c] = f2bf(sv[nb][r]);

#pragma unroll
  for (int ks = 0; ks < 2; ++ks) {
    bf16x8 pa = *(const bf16x8*)((const char*)p_w + c * 144 + ks * 64 + g * 16);
#pragma unroll
    for (int nb = 0; nb < 8; ++nb) {
      int n = (nb << 4) + c;
      int off = (n << 7) + (ks << 6) + (g << 4);
      bf16x8 vf = *(const bf16x8*)((const char*)v_lds + (off ^ ((n & 7) << 4)));
      acc_o[nb] = mfma16(pa, vf, acc_o[nb]);
    }
  }
}

// work map: j<256 -> (b=j>>5, qi=j&31, half0: tiles [0,T/2));
//           j>=256 -> (b, qi=31-(u&31), half1: tiles [T/2,T)). Pairs (j, j+256) balance.
__global__ __launch_bounds__(256) void flash_attn(
    const short* __restrict__ qp, const short* __restrict__ kp, const short* __restrict__ vt,
    const int* __restrict__ pad, float* __restrict__ partO, float* __restrict__ partML) {
  __shared__ short k_lds[2][64 * 128];
  __shared__ short v_lds[2][128 * 64];
  __shared__ short p_lds[4][16 * 72];
  const int tid = threadIdx.x, w = tid >> 6, lane = tid & 63;
  const int g = lane >> 4, c = lane & 15;
  const int j = blockIdx.x;
  int b, qi, half;
  if (j < 256) { b = j >> 5; qi = j & 31; half = 0; }
  else { int u = j - 256; b = u >> 5; qi = 31 - (u & 31); half = 1; }
  const int T = qi + 1;
  const int t0 = half ? (T >> 1) : 0;
  const int t1 = half ? T : (T >> 1);
  const int q0 = qi << 6;

  bf16x8 qf[4];
  {
    int token = (b << 11) + q0 + (w << 4) + c;
    const char* qrow = (const char*)qp + (size_t)token * 256;
#pragma unroll
    for (int s = 0; s < 4; ++s) qf[s] = *(const bf16x8*)(qrow + s * 64 + g * 16);
  }
  f32x4 acc_o[8];
#pragma unroll
  for (int i = 0; i < 8; ++i) acc_o[i] = (f32x4){0.f, 0.f, 0.f, 0.f};
  float m_r[4] = {-1e30f, -1e30f, -1e30f, -1e30f};
  float l_r[4] = {0.f, 0.f, 0.f, 0.f};

  const char* kb_base = (const char*)kp + (size_t)(b << 11) * 256;
  const char* vb_base = (const char*)vt + (size_t)b * 524288;
  const int* padp = pad + (b << 11);
  const int qrow_g = q0 + (w << 4) + (g << 2);

  if (t1 > t0) {
    stage_kv(k_lds[0], v_lds[0], kb_base, vb_base, t0, w, lane);
    __syncthreads();
    int cur = 0;
    for (int t = t0; t < t1; ++t) {
      if (t + 1 < t1)
        stage_kv(k_lds[cur ^ 1], v_lds[cur ^ 1], kb_base, vb_base, t + 1, w, lane);
      if (half && t == T - 1)
        attn_tile<true>(k_lds[cur], v_lds[cur], p_lds[w], qf, acc_o, m_r, l_r,
                        padp, t << 6, qrow_g, g, c);
      else
        attn_tile<false>(k_lds[cur], v_lds[cur], p_lds[w], qf, acc_o, m_r, l_r,
                         padp, t << 6, qrow_g, g, c);
      __syncthreads();
      cur ^= 1;
    }
  }

  float* pO = partO + (size_t)j * (64 * 128);
  float* pML = partML + (size_t)j * 128;
#pragma unroll
  for (int nb = 0; nb < 8; ++nb)
#pragma unroll
    for (int r = 0; r < 4; ++r)
      pO[(w * 16 + g * 4 + r) * 128 + (nb << 4) + c] = acc_o[nb][r];
  if (c == 0)
#pragma unroll
    for (int r = 0; r < 4; ++r) {
      pML[(w * 16 + g * 4 + r) * 2] = m_r[r];
      pML[(w * 16 + g * 4 + r) * 2 + 1] = l_r[r];
    }
}

// ---------------- combine: merge 2 partials, degenerate fixup ----------------
__global__ __launch_bounds__(256) void combine_kernel(
    const float* __restrict__ partO, const float* __restrict__ partML,
    const float* __restrict__ avgv, float* __restrict__ out) {
  int gid = blockIdx.x * 256 + threadIdx.x;   // 524288 float4s
  int row = gid >> 5;
  int d4 = gid & 31;
  int b = row >> 11, s = row & 2047;
  int qt = s >> 6, lr = s & 63;
  int wid1 = (b << 5) + qt;
  int wid2 = 256 + (b << 5) + (31 - qt);
  float m1 = partML[wid1 * 128 + lr * 2], l1 = partML[wid1 * 128 + lr * 2 + 1];
  float m2 = partML[wid2 * 128 + lr * 2], l2 = partML[wid2 * 128 + lr * 2 + 1];
  float m = fmaxf(m1, m2);
  f32x4 o;
  if (m < -1e8f) {
    o = *(const f32x4*)(avgv + (b << 7) + (d4 << 2));
  } else {
    float f1 = __expf(m1 - m), f2 = __expf(m2 - m);
    float inv = 1.0f / (l1 * f1 + l2 * f2);
    f32x4 o1 = *(const f32x4*)(partO + ((size_t)wid1 * 64 + lr) * 128 + (d4 << 2));
    f32x4 o2 = *(const f32x4*)(partO + ((size_t)wid2 * 64 + lr) * 128 + (d4 << 2));
#pragma unroll
    for (int k = 0; k < 4; ++k) o[k] = (o1[k] * f1 + o2[k] * f2) * inv;
  }
  *(f32x4*)(out + (size_t)row * 128 + (d4 << 2)) = o;
}

extern "C" void kernel_launch(void* const* d_in, const int* in_sizes, int n_in,
                              void* d_out, int out_size, void* d_ws, size_t ws_size,
                              hipStream_t stream) {
  const int*   pad   = (const int*)d_in[0];
  const float* query = (const float*)d_in[1];
  const float* key   = (const float*)d_in[2];
  const float* value = (const float*)d_in[3];
  const float* Wq    = (const float*)d_in[4];
  const float* bq    = (const float*)d_in[5];
  const float* Wk    = (const float*)d_in[6];
  const float* bk    = (const float*)d_in[7];
  const float* Wv    = (const float*)d_in[8];
  const float* bv    = (const float*)d_in[9];
  char* ws = (char*)d_ws;
  short* wt    = (short*)ws;                      // 768KB (fragment-ordered)
  short* qp    = (short*)(ws + 786432);           // 4MB
  short* kp    = (short*)(ws + 4980736);          // 4MB
  short* vt    = (short*)(ws + 9175040);          // 4MB  vT[8][128][2048]
  float* partO = (float*)(ws + 13369344);         // 512*64*128*4 = 16MB
  float* partML= (float*)(ws + 30146560);         // 512*64*2*4 = 256KB
  float* avgv  = (float*)(ws + 30408704);         // 4KB
  float* out   = (float*)d_out;

  prep_weights<<<dim3(192), dim3(256), 0, stream>>>(Wq, Wk, Wv, wt);
  proj_gemm<<<dim3(768), dim3(256), 0, stream>>>(query, key, value, wt, bq, bk, bv, qp, kp, vt);
  avgv2_kernel<<<dim3(64), dim3(256), 0, stream>>>(vt, pad, bv, avgv);
  flash_attn<<<dim3(512), dim3(256), 0, stream>>>(qp, kp, vt, pad, partO, partML);
  combine_kernel<<<dim3(2048), dim3(256), 0, stream>>>(partO, partML, avgv, out);
}